// Round 11
// baseline (59.715 us; speedup 1.0000x reference)
//
#include <hip/hip_runtime.h>
#include <math.h>

#define B_   2
#define CTX_ 512
#define C_   16
#define RS_  16
#define RT_  16
#define T_   34      // 2 + 2*RT
#define L_   128
#define K_   11
#define H_   1024
#define EPS_ 1e-12f

#define NSPLIT_  4
#define LCHUNK_  32                      // L_ / NSPLIT_
#define NBLKTR_  (T_ * C_ * NSPLIT_)     // 2176

typedef float vfloat4 __attribute__((ext_vector_type(4)));

__device__ __forceinline__ float siglog(float v) {
    return copysignf(log1pf(fabsf(v)), v);
}

// ---------------- Kernel 1: xt = x@W + b; xm; x2 = (xr+ixi)^2 ----------------
__global__ __launch_bounds__(512) void k_ctx(const float* __restrict__ x,
                                             const float* __restrict__ Wc,
                                             const float* __restrict__ bc,
                                             float2* __restrict__ x2out) {
    __shared__ float xrow[CTX_];
    __shared__ float xt[4 * L_];
    const int b = blockIdx.x;
    const int tid = threadIdx.x;
    xrow[tid] = x[b * CTX_ + tid];
    __syncthreads();
    float sum = bc[tid];
#pragma unroll 16
    for (int c = 0; c < CTX_; ++c)
        sum = fmaf(xrow[c], Wc[c * (4 * L_) + tid], sum);
    xt[tid] = sum;
    __syncthreads();
    if (tid < L_) {
        float xr = xt[2 * tid]     * siglog(xt[2 * L_ + 2 * tid]);
        float xi = xt[2 * tid + 1] * siglog(xt[2 * L_ + 2 * tid + 1]);
        x2out[b * L_ + tid] = make_float2(xr * xr - xi * xi, 2.0f * xr * xi);
    }
}

// ---------------- Kernel 2: inline-asm reg-staged contraction (forced MLP) ---
// 2176 blocks x 256 threads; block = (tc = blk>>2, s = blk&3), 32 l's.
// Thread = (l = s*32 + tid>>3, r-pair = tid&7). The 22 float4 loads are
// VOLATILE INLINE-ASM global_load_dwordx4 -> the compiler CANNOT pair them
// with their uses; one explicit s_waitcnt vmcnt(0) + sched_barrier(0)
// (rule #18) fences the compute. 22 loads in flight per thread, guaranteed.
__global__ __launch_bounds__(256, 2) void k_tr_part(const float4* __restrict__ A4,
                                                    const float4* __restrict__ B4,
                                                    const float2* __restrict__ x2g,
                                                    float* __restrict__ part) {
    const int blk = blockIdx.x;
    const int tc  = blk >> 2;
    const int s   = blk & 3;
    const int tid = threadIdx.x;
    const int rp  = tid & 7;
    const int l   = s * LCHUNK_ + (tid >> 3);

    const float4* __restrict__ Ab = A4 + ((size_t)(tc * L_ + l) * K_) * 8 + rp;
    const float4* __restrict__ Bb = B4 + ((size_t)tc * K_ * L_ + l) * 8 + rp;

    // x2 loads issued first; drained by the same explicit vmcnt(0)
    const float2 xv0 = x2g[l];
    const float2 xv1 = x2g[L_ + l];

    vfloat4 a[K_];
    vfloat4 bv[K_];
#pragma unroll
    for (int k = 0; k < K_; ++k)
        asm volatile("global_load_dwordx4 %0, %1, off"
                     : "=v"(a[k]) : "v"(Ab + (size_t)k * 8));
#pragma unroll
    for (int k = 0; k < K_; ++k)
        asm volatile("global_load_dwordx4 %0, %1, off"
                     : "=v"(bv[k]) : "v"(Bb + (size_t)k * L_ * 8));

    asm volatile("s_waitcnt vmcnt(0)" ::: "memory");
    __builtin_amdgcn_sched_barrier(0);

    float abr0 = 0.f, abi0 = 0.f, abr1 = 0.f, abi1 = 0.f;
#pragma unroll
    for (int k = 0; k < K_; ++k) {
        abr0 = fmaf(a[k].x, bv[k].x, abr0); abr0 = fmaf(-a[k].y, bv[k].y, abr0);
        abi0 = fmaf(a[k].x, bv[k].y, abi0); abi0 = fmaf( a[k].y, bv[k].x, abi0);
        abr1 = fmaf(a[k].z, bv[k].z, abr1); abr1 = fmaf(-a[k].w, bv[k].w, abr1);
        abi1 = fmaf(a[k].z, bv[k].w, abi1); abi1 = fmaf( a[k].w, bv[k].z, abi1);
    }

    // 12 accumulators: [b][pair][{Re,Im,M}]
    float acc[12];
    {
        float Re0 = xv0.x * abr0 - xv0.y * abi0;
        float Im0 = xv0.x * abi0 + xv0.y * abr0;
        float Re1 = xv0.x * abr1 - xv0.y * abi1;
        float Im1 = xv0.x * abi1 + xv0.y * abr1;
        acc[0] = Re0; acc[1] = Im0;
        acc[2] = sqrtf(fmaf(Re0, Re0, fmaf(Im0, Im0, EPS_)));
        acc[3] = Re1; acc[4] = Im1;
        acc[5] = sqrtf(fmaf(Re1, Re1, fmaf(Im1, Im1, EPS_)));
    }
    {
        float Re0 = xv1.x * abr0 - xv1.y * abi0;
        float Im0 = xv1.x * abi0 + xv1.y * abr0;
        float Re1 = xv1.x * abr1 - xv1.y * abi1;
        float Im1 = xv1.x * abi1 + xv1.y * abr1;
        acc[6] = Re0; acc[7] = Im0;
        acc[8] = sqrtf(fmaf(Re0, Re0, fmaf(Im0, Im0, EPS_)));
        acc[9] = Re1; acc[10] = Im1;
        acc[11] = sqrtf(fmaf(Re1, Re1, fmaf(Im1, Im1, EPS_)));
    }

    // butterfly over the 8 l's within the wave (lane bits 3,4,5)
#pragma unroll
    for (int off = 8; off <= 32; off <<= 1) {
#pragma unroll
        for (int i = 0; i < 12; ++i)
            acc[i] += __shfl_xor(acc[i], off);
    }

    __shared__ float wred[4][8][12];
    const int wave = tid >> 6;
    const int lane = tid & 63;
    if (lane < 8) {
#pragma unroll
        for (int i = 0; i < 12; ++i) wred[wave][lane][i] = acc[i];
    }
    __syncthreads();

    // 96 outputs: comp = (b*2+pair)*3 + c3, r = 2*rpi + pair
    if (tid < 96) {
        const int rpi  = tid / 12;          // 0..7
        const int comp = tid % 12;
        float v = wred[0][rpi][comp] + wred[1][rpi][comp]
                + wred[2][rpi][comp] + wred[3][rpi][comp];
        const int b    = comp / 6;
        const int pair = (comp / 3) & 1;
        const int c3   = comp % 3;
        const int r    = 2 * rpi + pair;
        atomicAdd(&part[(((size_t)tc * B_ + b) * RS_ + r) * 3 + c3], v);
    }
}

// ---------------- Kernel 3: fused finalize + apply_space ---------------------
__device__ __forceinline__ float2 tr_at(const float* __restrict__ part,
                                        int t, int c, int b, int r) {
    const int tc = t * C_ + c;
    const size_t base = (((size_t)tc * B_ + b) * RS_ + r) * 3;
    const float a0 = part[base + 0];
    const float a1 = part[base + 1];
    const float a2 = part[base + 2];
    const float inv = a2 / ((a2 + EPS_) * (float)L_);
    return make_float2(a0 * inv, a1 * inv);
}

__global__ __launch_bounds__(256) void k_out(const float4* __restrict__ space_i4,
                                             const float4* __restrict__ space_j4,
                                             const float* __restrict__ part,
                                             float4* __restrict__ out4) {
    const int halfq = B_ * C_ * RS_ * H_ / 2;   // 262144 float4 per output half
    int idx = blockIdx.x * blockDim.x + threadIdx.x;
    if (idx >= 2 * halfq) return;
    const int which = (idx >= halfq) ? 1 : 0;
    int id = idx - which * halfq;

    const int h2 = id & (H_ / 2 - 1);           // float4 index along h
    int rest = id >> 9;
    const int r = rest & 15; rest >>= 4;
    const int c = rest & 15;
    const int b = rest >> 4;

    const float4* __restrict__ sp4 = which ? space_j4 : space_i4;

    const float2 sh = tr_at(part, which, c, b, r);
    const int tb = 2 + which * RT_;

    const float4 sv = sp4[((size_t)c * RS_ + r) * (H_ / 2) + h2];

    float res[4];
#pragma unroll
    for (int u = 0; u < 2; ++u) {
        const int h = 2 * h2 + u;
        float pos = (h + 0.5f) * (16.0f / 1024.0f) - 0.5f;
        pos = fminf(fmaxf(pos, 0.0f), 15.0f);
        const int i0 = (int)floorf(pos);
        const int i1 = min(i0 + 1, RT_ - 1);
        const float w = pos - (float)i0;

        const float2 z0 = tr_at(part, tb + i0, c, b, r);
        const float2 z1 = tr_at(part, tb + i1, c, b, r);
        const float zx = z0.x * (1.0f - w) + z1.x * w;
        const float zy = z0.y * (1.0f - w) + z1.y * w;

        const float sx = (u ? sv.z : sv.x) + sh.x;
        const float sy = (u ? sv.w : sv.y) + sh.y;

        res[2 * u + 0] = sy * zy - sx * zx;
        res[2 * u + 1] = sx * zy + sy * zx;
    }
    vfloat4 rv;
    rv.x = res[0]; rv.y = res[1]; rv.z = res[2]; rv.w = res[3];
    __builtin_nontemporal_store(rv, (vfloat4*)&out4[idx]);
}

extern "C" void kernel_launch(void* const* d_in, const int* in_sizes, int n_in,
                              void* d_out, int out_size, void* d_ws, size_t ws_size,
                              hipStream_t stream) {
    const float*  x  = (const float*)d_in[0];
    const float*  Wc = (const float*)d_in[1];
    const float*  bc = (const float*)d_in[2];
    const float4* A4 = (const float4*)d_in[3];
    const float4* B4 = (const float4*)d_in[4];
    const float4* si = (const float4*)d_in[5];
    const float4* sj = (const float4*)d_in[6];

    float2* x2   = (float2*)d_ws;                                  // 2 KB
    float*  part = (float*)((char*)d_ws + 4096);                   // 209 KB

    const size_t part_bytes = (size_t)T_ * C_ * B_ * RS_ * 3 * sizeof(float);
    (void)hipMemsetAsync(part, 0, part_bytes, stream);

    k_ctx<<<B_, 512, 0, stream>>>(x, Wc, bc, x2);

    k_tr_part<<<NBLKTR_, 256, 0, stream>>>(A4, B4, x2, part);

    const int totalq = 2 * B_ * C_ * RS_ * H_ / 2;
    k_out<<<(totalq + 255) / 256, 256, 0, stream>>>(si, sj, part, (float4*)d_out);
}

// Round 12
// 59.687 us; speedup vs baseline: 1.0005x; 1.0005x over previous
//
#include <hip/hip_runtime.h>
#include <math.h>

#define B_   2
#define CTX_ 512
#define C_   16
#define RS_  16
#define RT_  16
#define T_   34      // 2 + 2*RT
#define L_   128
#define K_   11
#define H_   1024
#define EPS_ 1e-12f

#define NSPLIT_  4
#define LCHUNK_  32                      // L_ / NSPLIT_
#define NBLKTR_  (T_ * C_ * NSPLIT_)     // 2176

typedef float vfloat4 __attribute__((ext_vector_type(4)));

__device__ __forceinline__ float siglog(float v) {
    return copysignf(log1pf(fabsf(v)), v);
}

// ---------------- Kernel 1: xt = x@W + b; xm; x2 = (xr+ixi)^2 ----------------
__global__ __launch_bounds__(512) void k_ctx(const float* __restrict__ x,
                                             const float* __restrict__ Wc,
                                             const float* __restrict__ bc,
                                             float2* __restrict__ x2out) {
    __shared__ float xrow[CTX_];
    __shared__ float xt[4 * L_];
    const int b = blockIdx.x;
    const int tid = threadIdx.x;
    xrow[tid] = x[b * CTX_ + tid];
    __syncthreads();
    float sum = bc[tid];
#pragma unroll 16
    for (int c = 0; c < CTX_; ++c)
        sum = fmaf(xrow[c], Wc[c * (4 * L_) + tid], sum);
    xt[tid] = sum;
    __syncthreads();
    if (tid < L_) {
        float xr = xt[2 * tid]     * siglog(xt[2 * L_ + 2 * tid]);
        float xi = xt[2 * tid + 1] * siglog(xt[2 * L_ + 2 * tid + 1]);
        x2out[b * L_ + tid] = make_float2(xr * xr - xi * xi, 2.0f * xr * xi);
    }
}

// ---------------- Kernel 2: single-asm-block forced-MLP contraction ----------
// 2176 blocks x 256 threads; block = (tc = blk>>2, s = blk&3), 32 l's.
// Thread = (l = s*32 + tid>>3, r-pair = tid&7). ALL 22 global_load_dwordx4
// plus the vmcnt(0) live in ONE asm volatile block with 22 "=&v" outputs:
// the compiler cannot split, pair, or spill inside it -> 22 loads in flight
// per thread, guaranteed. VGPR_Count >= ~110 is the diagnostic that it held.
__global__ __launch_bounds__(256, 2) void k_tr_part(const float4* __restrict__ A4,
                                                    const float4* __restrict__ B4,
                                                    const float2* __restrict__ x2g,
                                                    float* __restrict__ part) {
    const int blk = blockIdx.x;
    const int tc  = blk >> 2;
    const int s   = blk & 3;
    const int tid = threadIdx.x;
    const int rp  = tid & 7;
    const int l   = s * LCHUNK_ + (tid >> 3);

    const float4* __restrict__ Ab = A4 + ((size_t)(tc * L_ + l) * K_) * 8 + rp;
    const float4* __restrict__ Bb = B4 + ((size_t)tc * K_ * L_ + l) * 8 + rp;

    // x2 loads issued first; drained by the asm block's vmcnt(0)
    const float2 xv0 = x2g[l];
    const float2 xv1 = x2g[L_ + l];

    vfloat4 a0, a1, a2, a3, a4, a5, a6, a7, a8, a9, a10;
    vfloat4 b0, b1, b2, b3, b4, b5, b6, b7, b8, b9, b10;

    asm volatile(
        "global_load_dwordx4 %[a0],  %[pa], off\n\t"
        "global_load_dwordx4 %[a1],  %[pa], off offset:128\n\t"
        "global_load_dwordx4 %[a2],  %[pa], off offset:256\n\t"
        "global_load_dwordx4 %[a3],  %[pa], off offset:384\n\t"
        "global_load_dwordx4 %[a4],  %[pa], off offset:512\n\t"
        "global_load_dwordx4 %[a5],  %[pa], off offset:640\n\t"
        "global_load_dwordx4 %[a6],  %[pa], off offset:768\n\t"
        "global_load_dwordx4 %[a7],  %[pa], off offset:896\n\t"
        "global_load_dwordx4 %[a8],  %[pa], off offset:1024\n\t"
        "global_load_dwordx4 %[a9],  %[pa], off offset:1152\n\t"
        "global_load_dwordx4 %[a10], %[pa], off offset:1280\n\t"
        "global_load_dwordx4 %[b0],  %[p0], off\n\t"
        "global_load_dwordx4 %[b1],  %[p1], off\n\t"
        "global_load_dwordx4 %[b2],  %[p2], off\n\t"
        "global_load_dwordx4 %[b3],  %[p3], off\n\t"
        "global_load_dwordx4 %[b4],  %[p4], off\n\t"
        "global_load_dwordx4 %[b5],  %[p5], off\n\t"
        "global_load_dwordx4 %[b6],  %[p6], off\n\t"
        "global_load_dwordx4 %[b7],  %[p7], off\n\t"
        "global_load_dwordx4 %[b8],  %[p8], off\n\t"
        "global_load_dwordx4 %[b9],  %[p9], off\n\t"
        "global_load_dwordx4 %[b10], %[p10], off\n\t"
        "s_waitcnt vmcnt(0)"
        : [a0] "=&v"(a0), [a1] "=&v"(a1), [a2] "=&v"(a2), [a3] "=&v"(a3),
          [a4] "=&v"(a4), [a5] "=&v"(a5), [a6] "=&v"(a6), [a7] "=&v"(a7),
          [a8] "=&v"(a8), [a9] "=&v"(a9), [a10] "=&v"(a10),
          [b0] "=&v"(b0), [b1] "=&v"(b1), [b2] "=&v"(b2), [b3] "=&v"(b3),
          [b4] "=&v"(b4), [b5] "=&v"(b5), [b6] "=&v"(b6), [b7] "=&v"(b7),
          [b8] "=&v"(b8), [b9] "=&v"(b9), [b10] "=&v"(b10)
        : [pa] "v"(Ab),
          [p0] "v"(Bb),               [p1] "v"(Bb + 1 * L_ * 8),
          [p2] "v"(Bb + 2 * L_ * 8),  [p3] "v"(Bb + 3 * L_ * 8),
          [p4] "v"(Bb + 4 * L_ * 8),  [p5] "v"(Bb + 5 * L_ * 8),
          [p6] "v"(Bb + 6 * L_ * 8),  [p7] "v"(Bb + 7 * L_ * 8),
          [p8] "v"(Bb + 8 * L_ * 8),  [p9] "v"(Bb + 9 * L_ * 8),
          [p10] "v"(Bb + 10 * L_ * 8)
        : "memory");
    __builtin_amdgcn_sched_barrier(0);

    float abr0 = 0.f, abi0 = 0.f, abr1 = 0.f, abi1 = 0.f;
#define CFMA(AK, BK)                                                        \
    do {                                                                    \
        abr0 = fmaf((AK).x, (BK).x, abr0); abr0 = fmaf(-(AK).y, (BK).y, abr0); \
        abi0 = fmaf((AK).x, (BK).y, abi0); abi0 = fmaf( (AK).y, (BK).x, abi0); \
        abr1 = fmaf((AK).z, (BK).z, abr1); abr1 = fmaf(-(AK).w, (BK).w, abr1); \
        abi1 = fmaf((AK).z, (BK).w, abi1); abi1 = fmaf( (AK).w, (BK).z, abi1); \
    } while (0)
    CFMA(a0, b0);   CFMA(a1, b1);   CFMA(a2, b2);   CFMA(a3, b3);
    CFMA(a4, b4);   CFMA(a5, b5);   CFMA(a6, b6);   CFMA(a7, b7);
    CFMA(a8, b8);   CFMA(a9, b9);   CFMA(a10, b10);
#undef CFMA

    // 12 accumulators: [b][pair][{Re,Im,M}]
    float acc[12];
    {
        float Re0 = xv0.x * abr0 - xv0.y * abi0;
        float Im0 = xv0.x * abi0 + xv0.y * abr0;
        float Re1 = xv0.x * abr1 - xv0.y * abi1;
        float Im1 = xv0.x * abi1 + xv0.y * abr1;
        acc[0] = Re0; acc[1] = Im0;
        acc[2] = sqrtf(fmaf(Re0, Re0, fmaf(Im0, Im0, EPS_)));
        acc[3] = Re1; acc[4] = Im1;
        acc[5] = sqrtf(fmaf(Re1, Re1, fmaf(Im1, Im1, EPS_)));
    }
    {
        float Re0 = xv1.x * abr0 - xv1.y * abi0;
        float Im0 = xv1.x * abi0 + xv1.y * abr0;
        float Re1 = xv1.x * abr1 - xv1.y * abi1;
        float Im1 = xv1.x * abi1 + xv1.y * abr1;
        acc[6] = Re0; acc[7] = Im0;
        acc[8] = sqrtf(fmaf(Re0, Re0, fmaf(Im0, Im0, EPS_)));
        acc[9] = Re1; acc[10] = Im1;
        acc[11] = sqrtf(fmaf(Re1, Re1, fmaf(Im1, Im1, EPS_)));
    }

    // butterfly over the 8 l's within the wave (lane bits 3,4,5)
#pragma unroll
    for (int off = 8; off <= 32; off <<= 1) {
#pragma unroll
        for (int i = 0; i < 12; ++i)
            acc[i] += __shfl_xor(acc[i], off);
    }

    __shared__ float wred[4][8][12];
    const int wave = tid >> 6;
    const int lane = tid & 63;
    if (lane < 8) {
#pragma unroll
        for (int i = 0; i < 12; ++i) wred[wave][lane][i] = acc[i];
    }
    __syncthreads();

    // 96 outputs: comp = (b*2+pair)*3 + c3, r = 2*rpi + pair
    if (tid < 96) {
        const int rpi  = tid / 12;          // 0..7
        const int comp = tid % 12;
        float v = wred[0][rpi][comp] + wred[1][rpi][comp]
                + wred[2][rpi][comp] + wred[3][rpi][comp];
        const int b    = comp / 6;
        const int pair = (comp / 3) & 1;
        const int c3   = comp % 3;
        const int r    = 2 * rpi + pair;
        atomicAdd(&part[(((size_t)tc * B_ + b) * RS_ + r) * 3 + c3], v);
    }
}

// ---------------- Kernel 3: fused finalize + apply_space ---------------------
__device__ __forceinline__ float2 tr_at(const float* __restrict__ part,
                                        int t, int c, int b, int r) {
    const int tc = t * C_ + c;
    const size_t base = (((size_t)tc * B_ + b) * RS_ + r) * 3;
    const float a0 = part[base + 0];
    const float a1 = part[base + 1];
    const float a2 = part[base + 2];
    const float inv = a2 / ((a2 + EPS_) * (float)L_);
    return make_float2(a0 * inv, a1 * inv);
}

__global__ __launch_bounds__(256) void k_out(const float4* __restrict__ space_i4,
                                             const float4* __restrict__ space_j4,
                                             const float* __restrict__ part,
                                             float4* __restrict__ out4) {
    const int halfq = B_ * C_ * RS_ * H_ / 2;   // 262144 float4 per output half
    int idx = blockIdx.x * blockDim.x + threadIdx.x;
    if (idx >= 2 * halfq) return;
    const int which = (idx >= halfq) ? 1 : 0;
    int id = idx - which * halfq;

    const int h2 = id & (H_ / 2 - 1);           // float4 index along h
    int rest = id >> 9;
    const int r = rest & 15; rest >>= 4;
    const int c = rest & 15;
    const int b = rest >> 4;

    const float4* __restrict__ sp4 = which ? space_j4 : space_i4;

    const float2 sh = tr_at(part, which, c, b, r);
    const int tb = 2 + which * RT_;

    const float4 sv = sp4[((size_t)c * RS_ + r) * (H_ / 2) + h2];

    float res[4];
#pragma unroll
    for (int u = 0; u < 2; ++u) {
        const int h = 2 * h2 + u;
        float pos = (h + 0.5f) * (16.0f / 1024.0f) - 0.5f;
        pos = fminf(fmaxf(pos, 0.0f), 15.0f);
        const int i0 = (int)floorf(pos);
        const int i1 = min(i0 + 1, RT_ - 1);
        const float w = pos - (float)i0;

        const float2 z0 = tr_at(part, tb + i0, c, b, r);
        const float2 z1 = tr_at(part, tb + i1, c, b, r);
        const float zx = z0.x * (1.0f - w) + z1.x * w;
        const float zy = z0.y * (1.0f - w) + z1.y * w;

        const float sx = (u ? sv.z : sv.x) + sh.x;
        const float sy = (u ? sv.w : sv.y) + sh.y;

        res[2 * u + 0] = sy * zy - sx * zx;
        res[2 * u + 1] = sx * zy + sy * zx;
    }
    vfloat4 rv;
    rv.x = res[0]; rv.y = res[1]; rv.z = res[2]; rv.w = res[3];
    __builtin_nontemporal_store(rv, (vfloat4*)&out4[idx]);
}

extern "C" void kernel_launch(void* const* d_in, const int* in_sizes, int n_in,
                              void* d_out, int out_size, void* d_ws, size_t ws_size,
                              hipStream_t stream) {
    const float*  x  = (const float*)d_in[0];
    const float*  Wc = (const float*)d_in[1];
    const float*  bc = (const float*)d_in[2];
    const float4* A4 = (const float4*)d_in[3];
    const float4* B4 = (const float4*)d_in[4];
    const float4* si = (const float4*)d_in[5];
    const float4* sj = (const float4*)d_in[6];

    float2* x2   = (float2*)d_ws;                                  // 2 KB
    float*  part = (float*)((char*)d_ws + 4096);                   // 209 KB

    const size_t part_bytes = (size_t)T_ * C_ * B_ * RS_ * 3 * sizeof(float);
    (void)hipMemsetAsync(part, 0, part_bytes, stream);

    k_ctx<<<B_, 512, 0, stream>>>(x, Wc, bc, x2);

    k_tr_part<<<NBLKTR_, 256, 0, stream>>>(A4, B4, x2, part);

    const int totalq = 2 * B_ * C_ * RS_ * H_ / 2;
    k_out<<<(totalq + 255) / 256, 256, 0, stream>>>(si, sj, part, (float4*)d_out);
}

// Round 13
// 53.624 us; speedup vs baseline: 1.1136x; 1.1130x over previous
//
#include <hip/hip_runtime.h>
#include <math.h>

#define B_   2
#define CTX_ 512
#define C_   16
#define RS_  16
#define RT_  16
#define T_   34      // 2 + 2*RT
#define L_   128
#define K_   11
#define H_   1024
#define EPS_ 1e-12f

#define NSPLIT_  4
#define LCHUNK_  32                      // L_ / NSPLIT_
#define NBLKTR_  (T_ * C_ * NSPLIT_)     // 2176

typedef float vfloat4 __attribute__((ext_vector_type(4)));

__device__ __forceinline__ float siglog(float v) {
    return copysignf(log1pf(fabsf(v)), v);
}

// ---------------- Kernel 1: xt = x@W + b; xm; x2 = (xr+ixi)^2 ----------------
__global__ __launch_bounds__(512) void k_ctx(const float* __restrict__ x,
                                             const float* __restrict__ Wc,
                                             const float* __restrict__ bc,
                                             float2* __restrict__ x2out) {
    __shared__ float xrow[CTX_];
    __shared__ float xt[4 * L_];
    const int b = blockIdx.x;
    const int tid = threadIdx.x;
    xrow[tid] = x[b * CTX_ + tid];
    __syncthreads();
    float sum = bc[tid];
#pragma unroll 16
    for (int c = 0; c < CTX_; ++c)
        sum = fmaf(xrow[c], Wc[c * (4 * L_) + tid], sum);
    xt[tid] = sum;
    __syncthreads();
    if (tid < L_) {
        float xr = xt[2 * tid]     * siglog(xt[2 * L_ + 2 * tid]);
        float xi = xt[2 * tid + 1] * siglog(xt[2 * L_ + 2 * tid + 1]);
        x2out[b * L_ + tid] = make_float2(xr * xr - xi * xi, 2.0f * xr * xi);
    }
}

// ---------------- Kernel 2: single-asm-block contraction, NT loads -----------
// Identical to R12 except the 22 global_load_dwordx4 carry the `nt` cache
// policy: bypass L2/L3 allocation, stream the full 192 MB from HBM. Clean
// A/B against R12 isolates the cache-path variable.
__global__ __launch_bounds__(256, 2) void k_tr_part(const float4* __restrict__ A4,
                                                    const float4* __restrict__ B4,
                                                    const float2* __restrict__ x2g,
                                                    float* __restrict__ part) {
    const int blk = blockIdx.x;
    const int tc  = blk >> 2;
    const int s   = blk & 3;
    const int tid = threadIdx.x;
    const int rp  = tid & 7;
    const int l   = s * LCHUNK_ + (tid >> 3);

    const float4* __restrict__ Ab = A4 + ((size_t)(tc * L_ + l) * K_) * 8 + rp;
    const float4* __restrict__ Bb = B4 + ((size_t)tc * K_ * L_ + l) * 8 + rp;

    // x2 loads issued first; drained by the asm block's vmcnt(0)
    const float2 xv0 = x2g[l];
    const float2 xv1 = x2g[L_ + l];

    vfloat4 a0, a1, a2, a3, a4, a5, a6, a7, a8, a9, a10;
    vfloat4 b0, b1, b2, b3, b4, b5, b6, b7, b8, b9, b10;

    asm volatile(
        "global_load_dwordx4 %[a0],  %[pa], off nt\n\t"
        "global_load_dwordx4 %[a1],  %[pa], off offset:128 nt\n\t"
        "global_load_dwordx4 %[a2],  %[pa], off offset:256 nt\n\t"
        "global_load_dwordx4 %[a3],  %[pa], off offset:384 nt\n\t"
        "global_load_dwordx4 %[a4],  %[pa], off offset:512 nt\n\t"
        "global_load_dwordx4 %[a5],  %[pa], off offset:640 nt\n\t"
        "global_load_dwordx4 %[a6],  %[pa], off offset:768 nt\n\t"
        "global_load_dwordx4 %[a7],  %[pa], off offset:896 nt\n\t"
        "global_load_dwordx4 %[a8],  %[pa], off offset:1024 nt\n\t"
        "global_load_dwordx4 %[a9],  %[pa], off offset:1152 nt\n\t"
        "global_load_dwordx4 %[a10], %[pa], off offset:1280 nt\n\t"
        "global_load_dwordx4 %[b0],  %[p0], off nt\n\t"
        "global_load_dwordx4 %[b1],  %[p1], off nt\n\t"
        "global_load_dwordx4 %[b2],  %[p2], off nt\n\t"
        "global_load_dwordx4 %[b3],  %[p3], off nt\n\t"
        "global_load_dwordx4 %[b4],  %[p4], off nt\n\t"
        "global_load_dwordx4 %[b5],  %[p5], off nt\n\t"
        "global_load_dwordx4 %[b6],  %[p6], off nt\n\t"
        "global_load_dwordx4 %[b7],  %[p7], off nt\n\t"
        "global_load_dwordx4 %[b8],  %[p8], off nt\n\t"
        "global_load_dwordx4 %[b9],  %[p9], off nt\n\t"
        "global_load_dwordx4 %[b10], %[p10], off nt\n\t"
        "s_waitcnt vmcnt(0)"
        : [a0] "=&v"(a0), [a1] "=&v"(a1), [a2] "=&v"(a2), [a3] "=&v"(a3),
          [a4] "=&v"(a4), [a5] "=&v"(a5), [a6] "=&v"(a6), [a7] "=&v"(a7),
          [a8] "=&v"(a8), [a9] "=&v"(a9), [a10] "=&v"(a10),
          [b0] "=&v"(b0), [b1] "=&v"(b1), [b2] "=&v"(b2), [b3] "=&v"(b3),
          [b4] "=&v"(b4), [b5] "=&v"(b5), [b6] "=&v"(b6), [b7] "=&v"(b7),
          [b8] "=&v"(b8), [b9] "=&v"(b9), [b10] "=&v"(b10)
        : [pa] "v"(Ab),
          [p0] "v"(Bb),               [p1] "v"(Bb + 1 * L_ * 8),
          [p2] "v"(Bb + 2 * L_ * 8),  [p3] "v"(Bb + 3 * L_ * 8),
          [p4] "v"(Bb + 4 * L_ * 8),  [p5] "v"(Bb + 5 * L_ * 8),
          [p6] "v"(Bb + 6 * L_ * 8),  [p7] "v"(Bb + 7 * L_ * 8),
          [p8] "v"(Bb + 8 * L_ * 8),  [p9] "v"(Bb + 9 * L_ * 8),
          [p10] "v"(Bb + 10 * L_ * 8)
        : "memory");
    __builtin_amdgcn_sched_barrier(0);

    float abr0 = 0.f, abi0 = 0.f, abr1 = 0.f, abi1 = 0.f;
#define CFMA(AK, BK)                                                        \
    do {                                                                    \
        abr0 = fmaf((AK).x, (BK).x, abr0); abr0 = fmaf(-(AK).y, (BK).y, abr0); \
        abi0 = fmaf((AK).x, (BK).y, abi0); abi0 = fmaf( (AK).y, (BK).x, abi0); \
        abr1 = fmaf((AK).z, (BK).z, abr1); abr1 = fmaf(-(AK).w, (BK).w, abr1); \
        abi1 = fmaf((AK).z, (BK).w, abi1); abi1 = fmaf( (AK).w, (BK).z, abi1); \
    } while (0)
    CFMA(a0, b0);   CFMA(a1, b1);   CFMA(a2, b2);   CFMA(a3, b3);
    CFMA(a4, b4);   CFMA(a5, b5);   CFMA(a6, b6);   CFMA(a7, b7);
    CFMA(a8, b8);   CFMA(a9, b9);   CFMA(a10, b10);
#undef CFMA

    // 12 accumulators: [b][pair][{Re,Im,M}]
    float acc[12];
    {
        float Re0 = xv0.x * abr0 - xv0.y * abi0;
        float Im0 = xv0.x * abi0 + xv0.y * abr0;
        float Re1 = xv0.x * abr1 - xv0.y * abi1;
        float Im1 = xv0.x * abi1 + xv0.y * abr1;
        acc[0] = Re0; acc[1] = Im0;
        acc[2] = sqrtf(fmaf(Re0, Re0, fmaf(Im0, Im0, EPS_)));
        acc[3] = Re1; acc[4] = Im1;
        acc[5] = sqrtf(fmaf(Re1, Re1, fmaf(Im1, Im1, EPS_)));
    }
    {
        float Re0 = xv1.x * abr0 - xv1.y * abi0;
        float Im0 = xv1.x * abi0 + xv1.y * abr0;
        float Re1 = xv1.x * abr1 - xv1.y * abi1;
        float Im1 = xv1.x * abi1 + xv1.y * abr1;
        acc[6] = Re0; acc[7] = Im0;
        acc[8] = sqrtf(fmaf(Re0, Re0, fmaf(Im0, Im0, EPS_)));
        acc[9] = Re1; acc[10] = Im1;
        acc[11] = sqrtf(fmaf(Re1, Re1, fmaf(Im1, Im1, EPS_)));
    }

    // butterfly over the 8 l's within the wave (lane bits 3,4,5)
#pragma unroll
    for (int off = 8; off <= 32; off <<= 1) {
#pragma unroll
        for (int i = 0; i < 12; ++i)
            acc[i] += __shfl_xor(acc[i], off);
    }

    __shared__ float wred[4][8][12];
    const int wave = tid >> 6;
    const int lane = tid & 63;
    if (lane < 8) {
#pragma unroll
        for (int i = 0; i < 12; ++i) wred[wave][lane][i] = acc[i];
    }
    __syncthreads();

    // 96 outputs: comp = (b*2+pair)*3 + c3, r = 2*rpi + pair
    if (tid < 96) {
        const int rpi  = tid / 12;          // 0..7
        const int comp = tid % 12;
        float v = wred[0][rpi][comp] + wred[1][rpi][comp]
                + wred[2][rpi][comp] + wred[3][rpi][comp];
        const int b    = comp / 6;
        const int pair = (comp / 3) & 1;
        const int c3   = comp % 3;
        const int r    = 2 * rpi + pair;
        atomicAdd(&part[(((size_t)tc * B_ + b) * RS_ + r) * 3 + c3], v);
    }
}

// ---------------- Kernel 3: fused finalize + apply_space ---------------------
__device__ __forceinline__ float2 tr_at(const float* __restrict__ part,
                                        int t, int c, int b, int r) {
    const int tc = t * C_ + c;
    const size_t base = (((size_t)tc * B_ + b) * RS_ + r) * 3;
    const float a0 = part[base + 0];
    const float a1 = part[base + 1];
    const float a2 = part[base + 2];
    const float inv = a2 / ((a2 + EPS_) * (float)L_);
    return make_float2(a0 * inv, a1 * inv);
}

__global__ __launch_bounds__(256) void k_out(const float4* __restrict__ space_i4,
                                             const float4* __restrict__ space_j4,
                                             const float* __restrict__ part,
                                             float4* __restrict__ out4) {
    const int halfq = B_ * C_ * RS_ * H_ / 2;   // 262144 float4 per output half
    int idx = blockIdx.x * blockDim.x + threadIdx.x;
    if (idx >= 2 * halfq) return;
    const int which = (idx >= halfq) ? 1 : 0;
    int id = idx - which * halfq;

    const int h2 = id & (H_ / 2 - 1);           // float4 index along h
    int rest = id >> 9;
    const int r = rest & 15; rest >>= 4;
    const int c = rest & 15;
    const int b = rest >> 4;

    const float4* __restrict__ sp4 = which ? space_j4 : space_i4;

    const float2 sh = tr_at(part, which, c, b, r);
    const int tb = 2 + which * RT_;

    const float4 sv = sp4[((size_t)c * RS_ + r) * (H_ / 2) + h2];

    float res[4];
#pragma unroll
    for (int u = 0; u < 2; ++u) {
        const int h = 2 * h2 + u;
        float pos = (h + 0.5f) * (16.0f / 1024.0f) - 0.5f;
        pos = fminf(fmaxf(pos, 0.0f), 15.0f);
        const int i0 = (int)floorf(pos);
        const int i1 = min(i0 + 1, RT_ - 1);
        const float w = pos - (float)i0;

        const float2 z0 = tr_at(part, tb + i0, c, b, r);
        const float2 z1 = tr_at(part, tb + i1, c, b, r);
        const float zx = z0.x * (1.0f - w) + z1.x * w;
        const float zy = z0.y * (1.0f - w) + z1.y * w;

        const float sx = (u ? sv.z : sv.x) + sh.x;
        const float sy = (u ? sv.w : sv.y) + sh.y;

        res[2 * u + 0] = sy * zy - sx * zx;
        res[2 * u + 1] = sx * zy + sy * zx;
    }
    vfloat4 rv;
    rv.x = res[0]; rv.y = res[1]; rv.z = res[2]; rv.w = res[3];
    __builtin_nontemporal_store(rv, (vfloat4*)&out4[idx]);
}

extern "C" void kernel_launch(void* const* d_in, const int* in_sizes, int n_in,
                              void* d_out, int out_size, void* d_ws, size_t ws_size,
                              hipStream_t stream) {
    const float*  x  = (const float*)d_in[0];
    const float*  Wc = (const float*)d_in[1];
    const float*  bc = (const float*)d_in[2];
    const float4* A4 = (const float4*)d_in[3];
    const float4* B4 = (const float4*)d_in[4];
    const float4* si = (const float4*)d_in[5];
    const float4* sj = (const float4*)d_in[6];

    float2* x2   = (float2*)d_ws;                                  // 2 KB
    float*  part = (float*)((char*)d_ws + 4096);                   // 209 KB

    const size_t part_bytes = (size_t)T_ * C_ * B_ * RS_ * 3 * sizeof(float);
    (void)hipMemsetAsync(part, 0, part_bytes, stream);

    k_ctx<<<B_, 512, 0, stream>>>(x, Wc, bc, x2);

    k_tr_part<<<NBLKTR_, 256, 0, stream>>>(A4, B4, x2, part);

    const int totalq = 2 * B_ * C_ * RS_ * H_ / 2;
    k_out<<<(totalq + 255) / 256, 256, 0, stream>>>(si, sj, part, (float4*)d_out);
}